// Round 1
// baseline (2231.652 us; speedup 1.0000x reference)
//
#include <hip/hip_runtime.h>
#include <cstdint>
#include <cstddef>

#define SLOPE 0.2f
#define HEADS 8

// ---------------- fp32 tiled GEMM: C[M,Nc] = A[M,512] * B[512,Nc] ----------------
__global__ __launch_bounds__(256) void gemm_f32(const float* __restrict__ A,
                                                const float* __restrict__ B,
                                                float* __restrict__ C,
                                                int M, int Nc) {
  const int K = 512;
  __shared__ float As[16][65];  // [k][m], padded to 65 -> conflict-free scalar stores
  __shared__ float Bs[16][68];  // [k][n], padded to 68 (16B-aligned rows)
  int tid = threadIdx.x;
  int bm = blockIdx.x * 64, bn = blockIdx.y * 64;
  int tx = tid & 15, ty = tid >> 4;
  int arow = tid >> 2, acol = (tid & 3) << 2;   // A tile load: 64 rows x 16 cols (float4)
  int brow = tid >> 4, bcol = (tid & 15) << 2;  // B tile load: 16 rows x 64 cols (float4)
  float acc[4][4] = {};
  const bool avalid = (bm + arow) < M;
  const float* aptr = A + (size_t)(bm + arow) * K + acol;
  for (int k0 = 0; k0 < K; k0 += 16) {
    float4 av = make_float4(0.f, 0.f, 0.f, 0.f);
    if (avalid) av = *(const float4*)(aptr + k0);
    As[acol + 0][arow] = av.x;
    As[acol + 1][arow] = av.y;
    As[acol + 2][arow] = av.z;
    As[acol + 3][arow] = av.w;
    float4 bv = *(const float4*)(B + (size_t)(k0 + brow) * Nc + bn + bcol);
    *(float4*)&Bs[brow][bcol] = bv;
    __syncthreads();
#pragma unroll
    for (int kk = 0; kk < 16; ++kk) {
      float a0[4], b0[4];
#pragma unroll
      for (int i = 0; i < 4; ++i) a0[i] = As[kk][ty * 4 + i];
#pragma unroll
      for (int j = 0; j < 4; ++j) b0[j] = Bs[kk][tx * 4 + j];
#pragma unroll
      for (int i = 0; i < 4; ++i)
#pragma unroll
        for (int j = 0; j < 4; ++j) acc[i][j] = fmaf(a0[i], b0[j], acc[i][j]);
    }
    __syncthreads();
  }
#pragma unroll
  for (int i = 0; i < 4; ++i) {
    int r = bm + ty * 4 + i;
    if (r < M) {
#pragma unroll
      for (int j = 0; j < 4; ++j) C[(size_t)r * Nc + bn + tx * 4 + j] = acc[i][j];
    }
  }
}

// ---------------- el/er: per (node, head) dot with al/ar ----------------
__global__ void el_er_kernel(const float* __restrict__ feat, const float* __restrict__ al,
                             const float* __restrict__ ar, float* __restrict__ el,
                             float* __restrict__ er, int n, int D) {
  int gid = blockIdx.x * blockDim.x + threadIdx.x;
  if (gid >= n * HEADS) return;
  int node = gid >> 3, h = gid & 7;
  const float* f = feat + (size_t)node * HEADS * D + h * D;
  const float* alp = al + h * D;
  const float* arp = ar + h * D;
  float a = 0.f, b = 0.f;
  for (int d = 0; d < D; ++d) {
    float v = f[d];
    a = fmaf(v, alp[d], a);
    b = fmaf(v, arp[d], b);
  }
  el[gid] = a;
  er[gid] = b;
}

// ---------------- CSR build ----------------
__global__ void count_deg(const int* __restrict__ dst, int* __restrict__ deg, int e) {
  int gid = blockIdx.x * blockDim.x + threadIdx.x;
  if (gid < e) atomicAdd(&deg[dst[gid]], 1);
}

__global__ void scan_block(const int* __restrict__ deg, int* __restrict__ incl,
                           int* __restrict__ bsum, int n) {
  __shared__ int tmp[256];
  int t = threadIdx.x;
  int gid = blockIdx.x * 256 + t;
  int v = (gid < n) ? deg[gid] : 0;
  tmp[t] = v;
  __syncthreads();
  for (int off = 1; off < 256; off <<= 1) {
    int x = (t >= off) ? tmp[t - off] : 0;
    __syncthreads();
    tmp[t] += x;
    __syncthreads();
  }
  if (gid < n) incl[gid] = tmp[t];
  if (t == 255) bsum[blockIdx.x] = tmp[255];
}

__global__ void scan_small(const int* __restrict__ bsum, int* __restrict__ bbase, int nb) {
  // nb <= 512 required (here nb = ceil(100000/256) = 391)
  __shared__ int tmp[512];
  int t = threadIdx.x;
  int v = (t < nb) ? bsum[t] : 0;
  tmp[t] = v;
  __syncthreads();
  for (int off = 1; off < 512; off <<= 1) {
    int x = (t >= off) ? tmp[t - off] : 0;
    __syncthreads();
    tmp[t] += x;
    __syncthreads();
  }
  if (t < nb) bbase[t] = tmp[t] - v;  // exclusive
}

__global__ void finalize_offsets(const int* __restrict__ incl, const int* __restrict__ deg,
                                 const int* __restrict__ bbase, int* __restrict__ offsets,
                                 int n) {
  int gid = blockIdx.x * blockDim.x + threadIdx.x;
  if (gid >= n) return;
  int base = bbase[gid >> 8];
  offsets[gid] = incl[gid] - deg[gid] + base;
  if (gid == n - 1) offsets[n] = incl[gid] + base;
}

__global__ void scatter_edges(const int* __restrict__ src, const int* __restrict__ dst,
                              const int* __restrict__ offsets, int* __restrict__ cursor,
                              int* __restrict__ ssrc, int e) {
  int gid = blockIdx.x * blockDim.x + threadIdx.x;
  if (gid < e) {
    int d = dst[gid];
    int p = offsets[d] + atomicAdd(&cursor[d], 1);
    ssrc[p] = src[gid];
  }
}

// ---------------- per-dst-node softmax + weighted aggregation ----------------
template <int HD, int D, bool RELU>
__global__ __launch_bounds__(256) void aggregate(
    const float* __restrict__ feat, const float* __restrict__ el,
    const float* __restrict__ er, const int* __restrict__ offsets,
    const int* __restrict__ ssrc, const float* __restrict__ bias,
    float* __restrict__ out) {
  int node = blockIdx.x;
  int t = threadIdx.x;
  int s0 = offsets[node], s1 = offsets[node + 1];
  __shared__ float sm[HEADS], ssm[HEADS];
  __shared__ float salpha[64 * HEADS];
  if (t < HEADS) {
    float er_t = er[node * HEADS + t];
    float m = -INFINITY, ss = 0.f;
    for (int j = s0; j < s1; ++j) {
      int s = ssrc[j];
      float x = el[s * HEADS + t] + er_t;
      x = x > 0.f ? x : SLOPE * x;
      if (x > m) {
        ss = ss * __expf(m - x) + 1.f;
        m = x;
      } else {
        ss += __expf(x - m);
      }
    }
    sm[t] = m;
    ssm[t] = ss;
  }
  __syncthreads();
  float acc0 = 0.f, acc1 = 0.f;
  for (int c0 = s0; c0 < s1; c0 += 64) {
    int cnt = min(64, s1 - c0);
    for (int k = t; k < cnt * HEADS; k += 256) {
      int j = k >> 3, hh = k & 7;
      int s = ssrc[c0 + j];
      float x = el[s * HEADS + hh] + er[node * HEADS + hh];
      x = x > 0.f ? x : SLOPE * x;
      salpha[j * HEADS + hh] = __expf(x - sm[hh]) / ssm[hh];
    }
    __syncthreads();
    for (int j = 0; j < cnt; ++j) {
      int s = ssrc[c0 + j];
      const float* fp = feat + (size_t)s * HD;
      acc0 += salpha[j * HEADS + (t / D)] * fp[t];
      if (HD > 256) {
        int idx = t + 256;
        if (idx < HD) acc1 += salpha[j * HEADS + (idx / D)] * fp[idx];
      }
    }
    __syncthreads();
  }
  {
    float v = acc0 + bias[t];
    if (RELU) v = fmaxf(v, 0.f);
    out[(size_t)node * HD + t] = v;
  }
  if (HD > 256) {
    int idx = t + 256;
    if (idx < HD) {
      float v = acc1 + bias[idx];
      if (RELU) v = fmaxf(v, 0.f);
      out[(size_t)node * HD + idx] = v;
    }
  }
}

// ---------------- mean over heads ----------------
__global__ void mean_heads(const float* __restrict__ out2, float* __restrict__ out, int n) {
  int gid = blockIdx.x * blockDim.x + threadIdx.x;
  if (gid >= n * 40) return;
  int node = gid / 40, c = gid % 40;
  const float* p = out2 + (size_t)node * 320 + c;
  float s = 0.f;
#pragma unroll
  for (int h = 0; h < HEADS; ++h) s += p[h * 40];
  out[gid] = s * 0.125f;
}

extern "C" void kernel_launch(void* const* d_in, const int* in_sizes, int n_in,
                              void* d_out, int out_size, void* d_ws, size_t ws_size,
                              hipStream_t stream) {
  const float* features = (const float*)d_in[0];
  const float* W1 = (const float*)d_in[1];
  const float* al1 = (const float*)d_in[2];
  const float* ar1 = (const float*)d_in[3];
  const float* b1 = (const float*)d_in[4];
  const float* W2 = (const float*)d_in[5];
  const float* al2 = (const float*)d_in[6];
  const float* ar2 = (const float*)d_in[7];
  const float* b2 = (const float*)d_in[8];
  const int* src = (const int*)d_in[9];
  const int* dst = (const int*)d_in[10];
  float* out = (float*)d_out;

  const int n = in_sizes[0] / 512;  // 100000
  const int e = in_sizes[9];        // 500000

  char* p = (char*)d_ws;
  auto alloc = [&](size_t bytes) {
    char* r = p;
    p += (bytes + 255) & ~(size_t)255;
    return r;
  };
  float* feat1 = (float*)alloc((size_t)n * 512 * 4);
  float* hbuf = (float*)alloc((size_t)n * 512 * 4);   // layer-1 out (relu'd); reused as out2
  float* feat2 = (float*)alloc((size_t)n * 320 * 4);
  float* el1 = (float*)alloc((size_t)n * 8 * 4);
  float* er1 = (float*)alloc((size_t)n * 8 * 4);
  float* el2 = (float*)alloc((size_t)n * 8 * 4);
  float* er2 = (float*)alloc((size_t)n * 8 * 4);
  int* deg = (int*)alloc((size_t)n * 4);
  int* cursor = (int*)alloc((size_t)n * 4);
  int* incl = (int*)alloc((size_t)n * 4);
  int* offsets = (int*)alloc((size_t)(n + 1) * 4);
  int nb = (n + 255) / 256;
  int* bsum = (int*)alloc((size_t)nb * 4);
  int* bbase = (int*)alloc((size_t)nb * 4);
  int* ssrc = (int*)alloc((size_t)e * 4);
  float* out2 = hbuf;

  hipMemsetAsync(deg, 0, (size_t)n * 4, stream);
  hipMemsetAsync(cursor, 0, (size_t)n * 4, stream);

  int eb = (e + 255) / 256;
  count_deg<<<eb, 256, 0, stream>>>(dst, deg, e);
  scan_block<<<nb, 256, 0, stream>>>(deg, incl, bsum, n);
  scan_small<<<1, 512, 0, stream>>>(bsum, bbase, nb);
  finalize_offsets<<<nb, 256, 0, stream>>>(incl, deg, bbase, offsets, n);
  scatter_edges<<<eb, 256, 0, stream>>>(src, dst, offsets, cursor, ssrc, e);

  // ---- layer 1 ----
  dim3 g1((n + 63) / 64, 512 / 64);
  gemm_f32<<<g1, 256, 0, stream>>>(features, W1, feat1, n, 512);
  el_er_kernel<<<(n * 8 + 255) / 256, 256, 0, stream>>>(feat1, al1, ar1, el1, er1, n, 64);
  aggregate<512, 64, true><<<n, 256, 0, stream>>>(feat1, el1, er1, offsets, ssrc, b1, hbuf);

  // ---- layer 2 ----
  dim3 g2((n + 63) / 64, 320 / 64);
  gemm_f32<<<g2, 256, 0, stream>>>(hbuf, W2, feat2, n, 320);
  el_er_kernel<<<(n * 8 + 255) / 256, 256, 0, stream>>>(feat2, al2, ar2, el2, er2, n, 40);
  aggregate<320, 40, false><<<n, 256, 0, stream>>>(feat2, el2, er2, offsets, ssrc, b2, out2);

  mean_heads<<<(n * 40 + 255) / 256, 256, 0, stream>>>(out2, out, n);
}

// Round 4
// 1305.773 us; speedup vs baseline: 1.7091x; 1.7091x over previous
//
#include <hip/hip_runtime.h>
#include <cstdint>
#include <cstddef>

#define SLOPE 0.2f
#define HEADS 8

typedef __bf16 bf16_t;
typedef __bf16 bf16x8 __attribute__((ext_vector_type(8)));
typedef float f32x4 __attribute__((ext_vector_type(4)));

// ---------------- fp32 -> bf16 row-major convert (8 elems/thread) ----------------
__global__ void cvt_a_bf16(const float* __restrict__ in, bf16_t* __restrict__ out, long n8) {
  long gid = (long)blockIdx.x * blockDim.x + threadIdx.x;
  if (gid >= n8) return;
  const float4* ip = (const float4*)in;
  float4 v0 = ip[gid * 2], v1 = ip[gid * 2 + 1];
  bf16x8 o;
  o[0] = (bf16_t)v0.x; o[1] = (bf16_t)v0.y; o[2] = (bf16_t)v0.z; o[3] = (bf16_t)v0.w;
  o[4] = (bf16_t)v1.x; o[5] = (bf16_t)v1.y; o[6] = (bf16_t)v1.z; o[7] = (bf16_t)v1.w;
  ((bf16x8*)out)[gid] = o;
}

// ---------------- W [K,N] fp32 -> Bt [N,K] bf16 (transpose) ----------------
__global__ void cvt_w_t(const float* __restrict__ W, bf16_t* __restrict__ Bt, int K, int N) {
  int gid = blockIdx.x * blockDim.x + threadIdx.x;
  if (gid >= K * N) return;
  int nn = gid / K, kk = gid % K;
  Bt[gid] = (bf16_t)W[(size_t)kk * N + nn];
}

// ---------------- bf16 MFMA GEMM: C[M,Nc] = A[Mp,K] * Bt[Np,K]^T, fp32 out ----------------
// 128x128 tile, BK=64, 4 waves (2x2), each wave 64x64 (4x4 frags of 16x16x32 MFMA).
// LDS XOR-swizzle applied via pre-swizzled global source so glds dest stays linear (m173).
__global__ __launch_bounds__(256) void gemm_bf16(
    const bf16_t* __restrict__ A,   // [Mp][K] row-major bf16 (Mp multiple of 128, pads zeroed)
    const bf16_t* __restrict__ Bt,  // [Np][K] row-major bf16 (Np multiple of 128, pads zeroed)
    float* __restrict__ C,          // [M][Nc]
    int M, int Nc, int K) {
  __shared__ __align__(16) unsigned char lds[32768];  // A: [0,16K), B: [16K,32K)
  const int tid = threadIdx.x;
  const int wid = tid >> 6, lane = tid & 63;
  const int wm = wid >> 1, wn = wid & 1;
  const int bm = blockIdx.x * 128, bn = blockIdx.y * 128;
  const int quad = lane >> 4, lrow = lane & 15;

  f32x4 acc[4][4] = {};

  const int st_sub = wid * 8 + (lane >> 3);            // row within 32-row group
  const int st_k = 8 * ((lane & 7) ^ (lane >> 3));     // pre-swizzled source k
  const bf16_t* aSrc = A + (size_t)(bm + st_sub) * K + st_k;
  const bf16_t* bSrc = Bt + (size_t)(bn + st_sub) * K + st_k;

  const int xorv = (lrow & 7) << 4;
  const int aRdBase = (wm * 64 + lrow) * 128;          // + mf*2048 + kb
  const int bRdBase = (wn * 64 + lrow) * 128 + 16384;  // + nf*2048 + kb

  for (int k0 = 0; k0 < K; k0 += 64) {
    if (k0) __syncthreads();
#pragma unroll
    for (int i = 0; i < 4; ++i) {
      __builtin_amdgcn_global_load_lds(
          (const __attribute__((address_space(1))) void*)(aSrc + (size_t)i * 32 * K + k0),
          (__attribute__((address_space(3))) void*)(lds + (i * 4 + wid) * 1024), 16, 0, 0);
    }
#pragma unroll
    for (int i = 0; i < 4; ++i) {
      __builtin_amdgcn_global_load_lds(
          (const __attribute__((address_space(1))) void*)(bSrc + (size_t)i * 32 * K + k0),
          (__attribute__((address_space(3))) void*)(lds + 16384 + (i * 4 + wid) * 1024), 16, 0, 0);
    }
    __syncthreads();
#pragma unroll
    for (int kk = 0; kk < 2; ++kk) {
      bf16x8 af[4], bfr[4];
      const int kb = (kk * 64 + quad * 16) ^ xorv;
#pragma unroll
      for (int mf = 0; mf < 4; ++mf)
        af[mf] = *(const bf16x8*)(lds + aRdBase + mf * 2048 + kb);
#pragma unroll
      for (int nf = 0; nf < 4; ++nf)
        bfr[nf] = *(const bf16x8*)(lds + bRdBase + nf * 2048 + kb);
#pragma unroll
      for (int mf = 0; mf < 4; ++mf)
#pragma unroll
        for (int nf = 0; nf < 4; ++nf)
          acc[mf][nf] =
              __builtin_amdgcn_mfma_f32_16x16x32_bf16(af[mf], bfr[nf], acc[mf][nf], 0, 0, 0);
    }
  }

  // C/D layout (verified m89/m91): col = lane&15, row = (lane>>4)*4 + reg
  const int crow0 = bm + wm * 64 + quad * 4;
  const int ccol0 = bn + wn * 64 + lrow;
#pragma unroll
  for (int mf = 0; mf < 4; ++mf) {
#pragma unroll
    for (int r = 0; r < 4; ++r) {
      int row = crow0 + mf * 16 + r;
      if (row < M) {
#pragma unroll
        for (int nf = 0; nf < 4; ++nf) {
          int col = ccol0 + nf * 16;
          if (col < Nc) C[(size_t)row * Nc + col] = acc[mf][nf][r];
        }
      }
    }
  }
}

// ---------------- el/er: per (node, head) dot with al/ar ----------------
__global__ void el_er_kernel(const float* __restrict__ feat, const float* __restrict__ al,
                             const float* __restrict__ ar, float* __restrict__ el,
                             float* __restrict__ er, int n, int D) {
  int gid = blockIdx.x * blockDim.x + threadIdx.x;
  if (gid >= n * HEADS) return;
  int node = gid >> 3, h = gid & 7;
  const float* f = feat + (size_t)node * HEADS * D + h * D;
  const float* alp = al + h * D;
  const float* arp = ar + h * D;
  float a = 0.f, b = 0.f;
  for (int d = 0; d < D; ++d) {
    float v = f[d];
    a = fmaf(v, alp[d], a);
    b = fmaf(v, arp[d], b);
  }
  el[gid] = a;
  er[gid] = b;
}

// ---------------- CSR build ----------------
__global__ void count_deg(const int* __restrict__ dst, int* __restrict__ deg, int e) {
  int gid = blockIdx.x * blockDim.x + threadIdx.x;
  if (gid < e) atomicAdd(&deg[dst[gid]], 1);
}

__global__ void scan_block(const int* __restrict__ deg, int* __restrict__ incl,
                           int* __restrict__ bsum, int n) {
  __shared__ int tmp[256];
  int t = threadIdx.x;
  int gid = blockIdx.x * 256 + t;
  int v = (gid < n) ? deg[gid] : 0;
  tmp[t] = v;
  __syncthreads();
  for (int off = 1; off < 256; off <<= 1) {
    int x = (t >= off) ? tmp[t - off] : 0;
    __syncthreads();
    tmp[t] += x;
    __syncthreads();
  }
  if (gid < n) incl[gid] = tmp[t];
  if (t == 255) bsum[blockIdx.x] = tmp[255];
}

__global__ void scan_small(const int* __restrict__ bsum, int* __restrict__ bbase, int nb) {
  __shared__ int tmp[512];
  int t = threadIdx.x;
  int v = (t < nb) ? bsum[t] : 0;
  tmp[t] = v;
  __syncthreads();
  for (int off = 1; off < 512; off <<= 1) {
    int x = (t >= off) ? tmp[t - off] : 0;
    __syncthreads();
    tmp[t] += x;
    __syncthreads();
  }
  if (t < nb) bbase[t] = tmp[t] - v;  // exclusive
}

__global__ void finalize_offsets(const int* __restrict__ incl, const int* __restrict__ deg,
                                 const int* __restrict__ bbase, int* __restrict__ offsets,
                                 int n) {
  int gid = blockIdx.x * blockDim.x + threadIdx.x;
  if (gid >= n) return;
  int base = bbase[gid >> 8];
  offsets[gid] = incl[gid] - deg[gid] + base;
  if (gid == n - 1) offsets[n] = incl[gid] + base;
}

__global__ void scatter_edges(const int* __restrict__ src, const int* __restrict__ dst,
                              const int* __restrict__ offsets, int* __restrict__ cursor,
                              int* __restrict__ ssrc, int e) {
  int gid = blockIdx.x * blockDim.x + threadIdx.x;
  if (gid < e) {
    int d = dst[gid];
    int p = offsets[d] + atomicAdd(&cursor[d], 1);
    ssrc[p] = src[gid];
  }
}

// ---------------- per-dst-node softmax + weighted aggregation ----------------
template <int HD, int D, bool RELU, typename OutT>
__global__ __launch_bounds__(256) void aggregate(
    const float* __restrict__ feat, const float* __restrict__ el,
    const float* __restrict__ er, const int* __restrict__ offsets,
    const int* __restrict__ ssrc, const float* __restrict__ bias,
    OutT* __restrict__ out) {
  int node = blockIdx.x;
  int t = threadIdx.x;
  int s0 = offsets[node], s1 = offsets[node + 1];
  __shared__ float sm[HEADS], ssm[HEADS];
  __shared__ float salpha[64 * HEADS];
  if (t < HEADS) {
    float er_t = er[node * HEADS + t];
    float m = -INFINITY, ss = 0.f;
    for (int j = s0; j < s1; ++j) {
      int s = ssrc[j];
      float x = el[s * HEADS + t] + er_t;
      x = x > 0.f ? x : SLOPE * x;
      if (x > m) {
        ss = ss * __expf(m - x) + 1.f;
        m = x;
      } else {
        ss += __expf(x - m);
      }
    }
    sm[t] = m;
    ssm[t] = ss;
  }
  __syncthreads();
  float acc0 = 0.f, acc1 = 0.f;
  for (int c0 = s0; c0 < s1; c0 += 64) {
    int cnt = min(64, s1 - c0);
    for (int k = t; k < cnt * HEADS; k += 256) {
      int j = k >> 3, hh = k & 7;
      int s = ssrc[c0 + j];
      float x = el[s * HEADS + hh] + er[node * HEADS + hh];
      x = x > 0.f ? x : SLOPE * x;
      salpha[j * HEADS + hh] = __expf(x - sm[hh]) / ssm[hh];
    }
    __syncthreads();
    for (int j = 0; j < cnt; ++j) {
      int s = ssrc[c0 + j];
      const float* fp = feat + (size_t)s * HD;
      acc0 += salpha[j * HEADS + (t / D)] * fp[t];
      if (HD > 256) {
        int idx = t + 256;
        if (idx < HD) acc1 += salpha[j * HEADS + (idx / D)] * fp[idx];
      }
    }
    __syncthreads();
  }
  {
    float v = acc0 + bias[t];
    if (RELU) v = fmaxf(v, 0.f);
    out[(size_t)node * HD + t] = (OutT)v;
  }
  if (HD > 256) {
    int idx = t + 256;
    if (idx < HD) {
      float v = acc1 + bias[idx];
      if (RELU) v = fmaxf(v, 0.f);
      out[(size_t)node * HD + idx] = (OutT)v;
    }
  }
}

// ---------------- mean over heads ----------------
__global__ void mean_heads(const float* __restrict__ out2, float* __restrict__ out, int n) {
  int gid = blockIdx.x * blockDim.x + threadIdx.x;
  if (gid >= n * 40) return;
  int node = gid / 40, c = gid % 40;
  const float* p = out2 + (size_t)node * 320 + c;
  float s = 0.f;
#pragma unroll
  for (int h = 0; h < HEADS; ++h) s += p[h * 40];
  out[gid] = s * 0.125f;
}

extern "C" void kernel_launch(void* const* d_in, const int* in_sizes, int n_in,
                              void* d_out, int out_size, void* d_ws, size_t ws_size,
                              hipStream_t stream) {
  const float* features = (const float*)d_in[0];
  const float* W1 = (const float*)d_in[1];
  const float* al1 = (const float*)d_in[2];
  const float* ar1 = (const float*)d_in[3];
  const float* b1 = (const float*)d_in[4];
  const float* W2 = (const float*)d_in[5];
  const float* al2 = (const float*)d_in[6];
  const float* ar2 = (const float*)d_in[7];
  const float* b2 = (const float*)d_in[8];
  const int* src = (const int*)d_in[9];
  const int* dst = (const int*)d_in[10];
  float* out = (float*)d_out;

  const int n = in_sizes[0] / 512;         // 100000
  const int e = in_sizes[9];               // 500000
  const int Mp = ((n + 127) / 128) * 128;  // 100096

  char* p = (char*)d_ws;
  auto alloc = [&](size_t bytes) {
    char* r = p;
    p += (bytes + 255) & ~(size_t)255;
    return r;
  };
  // Region 0: feat1 fp32 [n,512]; reused as out2 [n,320] after aggregate L1.
  float* feat1 = (float*)alloc((size_t)n * 512 * 4);  // 204.8 MB
  // Region 1 (shared): A1b bf16 [Mp,512] (102.5 MB, dead after gemm L1)
  //                    then feat2 fp32 [n,320] (128 MB, born at gemm L2).
  char* region1 = alloc((size_t)n * 320 * 4);  // 128 MB (>= Mp*512*2 = 102.5 MB)
  bf16_t* A1b = (bf16_t*)region1;
  float* feat2 = (float*)region1;
  // Region 2: hb bf16 [Mp,512] (relu'd layer-1 out).
  bf16_t* hb = (bf16_t*)alloc((size_t)Mp * 512 * 2);  // 102.5 MB
  bf16_t* W1t = (bf16_t*)alloc((size_t)512 * 512 * 2);
  bf16_t* W2t = (bf16_t*)alloc((size_t)384 * 512 * 2);
  float* el1 = (float*)alloc((size_t)n * 8 * 4);
  float* er1 = (float*)alloc((size_t)n * 8 * 4);
  float* el2 = (float*)alloc((size_t)n * 8 * 4);
  float* er2 = (float*)alloc((size_t)n * 8 * 4);
  int* deg = (int*)alloc((size_t)n * 4);
  int* cursor = (int*)alloc((size_t)n * 4);
  int* incl = (int*)alloc((size_t)n * 4);
  int* offsets = (int*)alloc((size_t)(n + 1) * 4);
  int nb = (n + 255) / 256;
  int* bsum = (int*)alloc((size_t)nb * 4);
  int* bbase = (int*)alloc((size_t)nb * 4);
  int* ssrc = (int*)alloc((size_t)e * 4);
  float* out2 = feat1;
  // total ~453 MB (round-1's 554 MB layout was proven OK; stay well below)

  hipMemsetAsync(deg, 0, (size_t)n * 4, stream);
  hipMemsetAsync(cursor, 0, (size_t)n * 4, stream);
  // Zero every pad region any kernel reads (avoid poisoned-ws reads entirely):
  hipMemsetAsync(A1b + (size_t)n * 512, 0, (size_t)(Mp - n) * 512 * 2, stream);
  hipMemsetAsync(hb + (size_t)n * 512, 0, (size_t)(Mp - n) * 512 * 2, stream);
  hipMemsetAsync(W2t + (size_t)320 * 512, 0, (size_t)64 * 512 * 2, stream);

  int eb = (e + 255) / 256;
  count_deg<<<eb, 256, 0, stream>>>(dst, deg, e);
  scan_block<<<nb, 256, 0, stream>>>(deg, incl, bsum, n);
  scan_small<<<1, 512, 0, stream>>>(bsum, bbase, nb);
  finalize_offsets<<<nb, 256, 0, stream>>>(incl, deg, bbase, offsets, n);
  scatter_edges<<<eb, 256, 0, stream>>>(src, dst, offsets, cursor, ssrc, e);

  // ---- bf16 operand prep ----
  long n8a = (long)n * 512 / 8;
  cvt_a_bf16<<<(int)((n8a + 255) / 256), 256, 0, stream>>>(features, A1b, n8a);
  cvt_w_t<<<(512 * 512 + 255) / 256, 256, 0, stream>>>(W1, W1t, 512, 512);
  cvt_w_t<<<(512 * 320 + 255) / 256, 256, 0, stream>>>(W2, W2t, 512, 320);

  // ---- layer 1 ----
  dim3 g1(Mp / 128, 512 / 128);
  gemm_bf16<<<g1, 256, 0, stream>>>(A1b, W1t, feat1, n, 512, 512);
  el_er_kernel<<<(n * 8 + 255) / 256, 256, 0, stream>>>(feat1, al1, ar1, el1, er1, n, 64);
  aggregate<512, 64, true, bf16_t><<<n, 256, 0, stream>>>(feat1, el1, er1, offsets, ssrc, b1, hb);

  // ---- layer 2 ---- (feat2 aliases A1b's region; A1b dead after gemm L1)
  dim3 g2(Mp / 128, 384 / 128);
  gemm_bf16<<<g2, 256, 0, stream>>>(hb, W2t, feat2, n, 320, 512);
  el_er_kernel<<<(n * 8 + 255) / 256, 256, 0, stream>>>(feat2, al2, ar2, el2, er2, n, 40);
  aggregate<320, 40, false, float><<<n, 256, 0, stream>>>(feat2, el2, er2, offsets, ssrc, b2, out2);

  mean_heads<<<(n * 40 + 255) / 256, 256, 0, stream>>>(out2, out, n);
}

// Round 5
// 727.136 us; speedup vs baseline: 3.0691x; 1.7958x over previous
//
#include <hip/hip_runtime.h>
#include <cstdint>
#include <cstddef>

#define SLOPE 0.2f
#define HEADS 8

typedef __bf16 bf16_t;
typedef __bf16 bf16x8 __attribute__((ext_vector_type(8)));
typedef float f32x4 __attribute__((ext_vector_type(4)));

// ---------------- fp32 -> bf16 row-major convert (8 elems/thread) ----------------
__global__ void cvt_a_bf16(const float* __restrict__ in, bf16_t* __restrict__ out, long n8) {
  long gid = (long)blockIdx.x * blockDim.x + threadIdx.x;
  if (gid >= n8) return;
  const float4* ip = (const float4*)in;
  float4 v0 = ip[gid * 2], v1 = ip[gid * 2 + 1];
  bf16x8 o;
  o[0] = (bf16_t)v0.x; o[1] = (bf16_t)v0.y; o[2] = (bf16_t)v0.z; o[3] = (bf16_t)v0.w;
  o[4] = (bf16_t)v1.x; o[5] = (bf16_t)v1.y; o[6] = (bf16_t)v1.z; o[7] = (bf16_t)v1.w;
  ((bf16x8*)out)[gid] = o;
}

// ---------------- W [K,N] fp32 -> Bt [N,K] bf16 (transpose) ----------------
__global__ void cvt_w_t(const float* __restrict__ W, bf16_t* __restrict__ Bt, int K, int N) {
  int gid = blockIdx.x * blockDim.x + threadIdx.x;
  if (gid >= K * N) return;
  int nn = gid / K, kk = gid % K;
  Bt[gid] = (bf16_t)W[(size_t)kk * N + nn];
}

// ---------------- bf16 MFMA GEMM: C[M,Nc] = A[Mp,K] * Bt[Np,K]^T, fp32 out ----------------
// 128x128 tile, BK=64, 4 waves (2x2), each wave 64x64 (4x4 frags of 16x16x32 MFMA).
// Optionally also emits a bf16 copy of C (Cb) for downstream bf16 gathers.
__global__ __launch_bounds__(256) void gemm_bf16(
    const bf16_t* __restrict__ A,   // [Mp][K] row-major bf16 (Mp multiple of 128, pads zeroed)
    const bf16_t* __restrict__ Bt,  // [Np][K] row-major bf16 (Np multiple of 128, pads zeroed)
    float* __restrict__ C,          // [M][Nc]
    bf16_t* __restrict__ Cb,        // optional [M][Nc] bf16 (may be null)
    int M, int Nc, int K) {
  __shared__ __align__(16) unsigned char lds[32768];  // A: [0,16K), B: [16K,32K)
  const int tid = threadIdx.x;
  const int wid = tid >> 6, lane = tid & 63;
  const int wm = wid >> 1, wn = wid & 1;
  const int bm = blockIdx.x * 128, bn = blockIdx.y * 128;
  const int quad = lane >> 4, lrow = lane & 15;

  f32x4 acc[4][4] = {};

  const int st_sub = wid * 8 + (lane >> 3);            // row within 32-row group
  const int st_k = 8 * ((lane & 7) ^ (lane >> 3));     // pre-swizzled source k
  const bf16_t* aSrc = A + (size_t)(bm + st_sub) * K + st_k;
  const bf16_t* bSrc = Bt + (size_t)(bn + st_sub) * K + st_k;

  const int xorv = (lrow & 7) << 4;
  const int aRdBase = (wm * 64 + lrow) * 128;          // + mf*2048 + kb
  const int bRdBase = (wn * 64 + lrow) * 128 + 16384;  // + nf*2048 + kb

  for (int k0 = 0; k0 < K; k0 += 64) {
    if (k0) __syncthreads();
#pragma unroll
    for (int i = 0; i < 4; ++i) {
      __builtin_amdgcn_global_load_lds(
          (const __attribute__((address_space(1))) void*)(aSrc + (size_t)i * 32 * K + k0),
          (__attribute__((address_space(3))) void*)(lds + (i * 4 + wid) * 1024), 16, 0, 0);
    }
#pragma unroll
    for (int i = 0; i < 4; ++i) {
      __builtin_amdgcn_global_load_lds(
          (const __attribute__((address_space(1))) void*)(bSrc + (size_t)i * 32 * K + k0),
          (__attribute__((address_space(3))) void*)(lds + 16384 + (i * 4 + wid) * 1024), 16, 0, 0);
    }
    __syncthreads();
#pragma unroll
    for (int kk = 0; kk < 2; ++kk) {
      bf16x8 af[4], bfr[4];
      const int kb = (kk * 64 + quad * 16) ^ xorv;
#pragma unroll
      for (int mf = 0; mf < 4; ++mf)
        af[mf] = *(const bf16x8*)(lds + aRdBase + mf * 2048 + kb);
#pragma unroll
      for (int nf = 0; nf < 4; ++nf)
        bfr[nf] = *(const bf16x8*)(lds + bRdBase + nf * 2048 + kb);
#pragma unroll
      for (int mf = 0; mf < 4; ++mf)
#pragma unroll
        for (int nf = 0; nf < 4; ++nf)
          acc[mf][nf] =
              __builtin_amdgcn_mfma_f32_16x16x32_bf16(af[mf], bfr[nf], acc[mf][nf], 0, 0, 0);
    }
  }

  // C/D layout (verified m89/m91): col = lane&15, row = (lane>>4)*4 + reg
  const int crow0 = bm + wm * 64 + quad * 4;
  const int ccol0 = bn + wn * 64 + lrow;
#pragma unroll
  for (int mf = 0; mf < 4; ++mf) {
#pragma unroll
    for (int r = 0; r < 4; ++r) {
      int row = crow0 + mf * 16 + r;
      if (row < M) {
#pragma unroll
        for (int nf = 0; nf < 4; ++nf) {
          int col = ccol0 + nf * 16;
          if (col < Nc) {
            float v = acc[mf][nf][r];
            C[(size_t)row * Nc + col] = v;
            if (Cb) Cb[(size_t)row * Nc + col] = (bf16_t)v;
          }
        }
      }
    }
  }
}

// ---------------- el/er: per (node, head) dot with al/ar (float4) ----------------
__global__ void el_er_kernel(const float* __restrict__ feat, const float* __restrict__ al,
                             const float* __restrict__ ar, float* __restrict__ el,
                             float* __restrict__ er, int n, int D) {
  int gid = blockIdx.x * blockDim.x + threadIdx.x;
  if (gid >= n * HEADS) return;
  int node = gid >> 3, h = gid & 7;
  const float* f = feat + (size_t)node * HEADS * D + h * D;
  const float* alp = al + h * D;
  const float* arp = ar + h * D;
  float a = 0.f, b = 0.f;
  for (int d = 0; d < D; d += 4) {
    float4 v = *(const float4*)(f + d);
    float4 va = *(const float4*)(alp + d);
    float4 vb = *(const float4*)(arp + d);
    a = fmaf(v.x, va.x, fmaf(v.y, va.y, fmaf(v.z, va.z, fmaf(v.w, va.w, a))));
    b = fmaf(v.x, vb.x, fmaf(v.y, vb.y, fmaf(v.z, vb.z, fmaf(v.w, vb.w, b))));
  }
  el[gid] = a;
  er[gid] = b;
}

// ---------------- CSR build ----------------
__global__ void count_deg(const int* __restrict__ dst, int* __restrict__ deg, int e) {
  int gid = blockIdx.x * blockDim.x + threadIdx.x;
  if (gid < e) atomicAdd(&deg[dst[gid]], 1);
}

__global__ void scan_block(const int* __restrict__ deg, int* __restrict__ incl,
                           int* __restrict__ bsum, int n) {
  __shared__ int tmp[256];
  int t = threadIdx.x;
  int gid = blockIdx.x * 256 + t;
  int v = (gid < n) ? deg[gid] : 0;
  tmp[t] = v;
  __syncthreads();
  for (int off = 1; off < 256; off <<= 1) {
    int x = (t >= off) ? tmp[t - off] : 0;
    __syncthreads();
    tmp[t] += x;
    __syncthreads();
  }
  if (gid < n) incl[gid] = tmp[t];
  if (t == 255) bsum[blockIdx.x] = tmp[255];
}

__global__ void scan_small(const int* __restrict__ bsum, int* __restrict__ bbase, int nb) {
  __shared__ int tmp[512];
  int t = threadIdx.x;
  int v = (t < nb) ? bsum[t] : 0;
  tmp[t] = v;
  __syncthreads();
  for (int off = 1; off < 512; off <<= 1) {
    int x = (t >= off) ? tmp[t - off] : 0;
    __syncthreads();
    tmp[t] += x;
    __syncthreads();
  }
  if (t < nb) bbase[t] = tmp[t] - v;  // exclusive
}

__global__ void finalize_offsets(const int* __restrict__ incl, const int* __restrict__ deg,
                                 const int* __restrict__ bbase, int* __restrict__ offsets,
                                 int n) {
  int gid = blockIdx.x * blockDim.x + threadIdx.x;
  if (gid >= n) return;
  int base = bbase[gid >> 8];
  offsets[gid] = incl[gid] - deg[gid] + base;
  if (gid == n - 1) offsets[n] = incl[gid] + base;
}

__global__ void scatter_edges(const int* __restrict__ src, const int* __restrict__ dst,
                              const int* __restrict__ offsets, int* __restrict__ cursor,
                              int* __restrict__ ssrc, int e) {
  int gid = blockIdx.x * blockDim.x + threadIdx.x;
  if (gid < e) {
    int d = dst[gid];
    int p = offsets[d] + atomicAdd(&cursor[d], 1);
    ssrc[p] = src[gid];
  }
}

// ---------------- wave-per-node online softmax (shared by both aggregates) ----------------
// lane = h*8 + strip. Returns (m, ss) valid in every lane of the 8-lane head group.
__device__ inline void wave_softmax_stats(const float* __restrict__ el, float er_h, int h,
                                          int strip, const int* __restrict__ ssrc, int s0,
                                          int s1, float& m, float& ss) {
  m = -INFINITY;
  ss = 0.f;
  for (int j = s0 + strip; j < s1; j += 8) {
    int s = ssrc[j];
    float x = el[s * HEADS + h] + er_h;
    x = x > 0.f ? x : SLOPE * x;
    if (x > m) {
      ss = ss * __expf(m - x) + 1.f;
      m = x;
    } else {
      ss += __expf(x - m);
    }
  }
#pragma unroll
  for (int mask = 1; mask < 8; mask <<= 1) {
    float mo = __shfl_xor(m, mask, 64);
    float so = __shfl_xor(ss, mask, 64);
    float mn = fmaxf(m, mo);
    float e1 = (m == -INFINITY) ? 0.f : __expf(m - mn);
    float e2 = (mo == -INFINITY) ? 0.f : __expf(mo - mn);
    ss = ss * e1 + so * e2;
    m = mn;
  }
}

// ---------------- layer-1 aggregate: HD=512, D=64, bf16 gather, relu, bf16 out ----------------
__global__ __launch_bounds__(256) void aggregate1(
    const bf16_t* __restrict__ featb, const float* __restrict__ el,
    const float* __restrict__ er, const int* __restrict__ offsets,
    const int* __restrict__ ssrc, const float* __restrict__ bias,
    bf16_t* __restrict__ outb, int n) {
  int wid = threadIdx.x >> 6, lane = threadIdx.x & 63;
  int node = blockIdx.x * 4 + wid;
  if (node >= n) return;
  int s0 = offsets[node], s1 = offsets[node + 1];
  int h = lane >> 3, strip = lane & 7;
  float er_h = er[node * HEADS + h];
  float m, ss;
  wave_softmax_stats(el, er_h, h, strip, ssrc, s0, s1, m, ss);
  float inv_ss = 1.f / ss;

  float acc[8] = {};
  for (int j = s0; j < s1; ++j) {
    int s = ssrc[j];
    float x = el[s * HEADS + h] + er_h;
    x = x > 0.f ? x : SLOPE * x;
    float alpha = __expf(x - m) * inv_ss;
    bf16x8 fv = *(const bf16x8*)(featb + (size_t)s * 512 + lane * 8);
#pragma unroll
    for (int i = 0; i < 8; ++i) acc[i] += alpha * (float)fv[i];
  }
  bf16x8 o;
#pragma unroll
  for (int i = 0; i < 8; ++i) {
    float v = acc[i] + bias[lane * 8 + i];
    o[i] = (bf16_t)fmaxf(v, 0.f);
  }
  *(bf16x8*)(outb + (size_t)node * 512 + lane * 8) = o;
}

// ---------------- layer-2 aggregate: HD=320, D=40, fp32 gather, fp32 out ----------------
__global__ __launch_bounds__(256) void aggregate2(
    const float* __restrict__ feat, const float* __restrict__ el,
    const float* __restrict__ er, const int* __restrict__ offsets,
    const int* __restrict__ ssrc, const float* __restrict__ bias,
    float* __restrict__ out, int n) {
  int wid = threadIdx.x >> 6, lane = threadIdx.x & 63;
  int node = blockIdx.x * 4 + wid;
  if (node >= n) return;
  int s0 = offsets[node], s1 = offsets[node + 1];
  int h = lane >> 3, strip = lane & 7;
  float er_h = er[node * HEADS + h];
  float m, ss;
  wave_softmax_stats(el, er_h, h, strip, ssrc, s0, s1, m, ss);
  float inv_ss = 1.f / ss;

  // element d = lane + k*64, alpha source lane = (d/40)*8 (static per k after unroll)
  int alane0 = ((lane + 0 * 64) / 40) * 8;
  int alane1 = ((lane + 1 * 64) / 40) * 8;
  int alane2 = ((lane + 2 * 64) / 40) * 8;
  int alane3 = ((lane + 3 * 64) / 40) * 8;
  int alane4 = ((lane + 4 * 64) / 40) * 8;

  float acc[5] = {};
  for (int j = s0; j < s1; ++j) {
    int s = ssrc[j];
    float x = el[s * HEADS + h] + er_h;
    x = x > 0.f ? x : SLOPE * x;
    float aown = __expf(x - m) * inv_ss;  // alpha for this lane's head h
    const float* fp = feat + (size_t)s * 320;
    acc[0] += __shfl(aown, alane0, 64) * fp[lane];
    acc[1] += __shfl(aown, alane1, 64) * fp[lane + 64];
    acc[2] += __shfl(aown, alane2, 64) * fp[lane + 128];
    acc[3] += __shfl(aown, alane3, 64) * fp[lane + 192];
    acc[4] += __shfl(aown, alane4, 64) * fp[lane + 256];
  }
#pragma unroll
  for (int k = 0; k < 5; ++k) {
    int d = lane + k * 64;
    out[(size_t)node * 320 + d] = acc[k] + bias[d];
  }
}

// ---------------- mean over heads ----------------
__global__ void mean_heads(const float* __restrict__ out2, float* __restrict__ out, int n) {
  int gid = blockIdx.x * blockDim.x + threadIdx.x;
  if (gid >= n * 40) return;
  int node = gid / 40, c = gid % 40;
  const float* p = out2 + (size_t)node * 320 + c;
  float s = 0.f;
#pragma unroll
  for (int h = 0; h < HEADS; ++h) s += p[h * 40];
  out[gid] = s * 0.125f;
}

extern "C" void kernel_launch(void* const* d_in, const int* in_sizes, int n_in,
                              void* d_out, int out_size, void* d_ws, size_t ws_size,
                              hipStream_t stream) {
  const float* features = (const float*)d_in[0];
  const float* W1 = (const float*)d_in[1];
  const float* al1 = (const float*)d_in[2];
  const float* ar1 = (const float*)d_in[3];
  const float* b1 = (const float*)d_in[4];
  const float* W2 = (const float*)d_in[5];
  const float* al2 = (const float*)d_in[6];
  const float* ar2 = (const float*)d_in[7];
  const float* b2 = (const float*)d_in[8];
  const int* src = (const int*)d_in[9];
  const int* dst = (const int*)d_in[10];
  float* out = (float*)d_out;

  const int n = in_sizes[0] / 512;         // 100000
  const int e = in_sizes[9];               // 500000
  const int Mp = ((n + 127) / 128) * 128;  // 100096

  char* p = (char*)d_ws;
  auto alloc = [&](size_t bytes) {
    char* r = p;
    p += (bytes + 255) & ~(size_t)255;
    return r;
  };
  // R0: feat1 fp32 [n,512] (gemm L1 out; dead after el_er L1) -> reused as out2 [n,320] fp32.
  float* feat1 = (float*)alloc((size_t)n * 512 * 4);  // 204.8 MB
  // R1: feat1b bf16 [n,512] (gemm L1 bf16 out; dead after aggregate1)
  //     -> feat2 fp32 [n,320] (born at gemm L2).  128 MB >= 102.4 MB.
  char* region1 = alloc((size_t)n * 320 * 4);  // 128 MB
  bf16_t* feat1b = (bf16_t*)region1;
  float* feat2 = (float*)region1;
  // R2: A1b bf16 [Mp,512] (cvt out, gemm L1 in; dead after gemm L1)
  //     -> hb bf16 [Mp,512] (aggregate1 out rows [0,n); pad rows stay zeroed from A1b init).
  bf16_t* A1b = (bf16_t*)alloc((size_t)Mp * 512 * 2);  // 102.5 MB
  bf16_t* hb = A1b;
  bf16_t* W1t = (bf16_t*)alloc((size_t)512 * 512 * 2);
  bf16_t* W2t = (bf16_t*)alloc((size_t)384 * 512 * 2);
  float* el1 = (float*)alloc((size_t)n * 8 * 4);
  float* er1 = (float*)alloc((size_t)n * 8 * 4);
  float* el2 = (float*)alloc((size_t)n * 8 * 4);
  float* er2 = (float*)alloc((size_t)n * 8 * 4);
  int* deg = (int*)alloc((size_t)n * 4);
  int* cursor = (int*)alloc((size_t)n * 4);
  int* incl = (int*)alloc((size_t)n * 4);
  int* offsets = (int*)alloc((size_t)(n + 1) * 4);
  int nb = (n + 255) / 256;
  int* bsum = (int*)alloc((size_t)nb * 4);
  int* bbase = (int*)alloc((size_t)nb * 4);
  int* ssrc = (int*)alloc((size_t)e * 4);
  float* out2 = feat1;
  // total ~443 MB (below the proven-safe 453 MB of round 4)

  hipMemsetAsync(deg, 0, (size_t)n * 4, stream);
  hipMemsetAsync(cursor, 0, (size_t)n * 4, stream);
  // Zero pad regions read by gemm kernels (A1b/hb pads persist zeroed; W2t pad rows).
  hipMemsetAsync(A1b + (size_t)n * 512, 0, (size_t)(Mp - n) * 512 * 2, stream);
  hipMemsetAsync(W2t + (size_t)320 * 512, 0, (size_t)64 * 512 * 2, stream);

  int eb = (e + 255) / 256;
  count_deg<<<eb, 256, 0, stream>>>(dst, deg, e);
  scan_block<<<nb, 256, 0, stream>>>(deg, incl, bsum, n);
  scan_small<<<1, 512, 0, stream>>>(bsum, bbase, nb);
  finalize_offsets<<<nb, 256, 0, stream>>>(incl, deg, bbase, offsets, n);
  scatter_edges<<<eb, 256, 0, stream>>>(src, dst, offsets, cursor, ssrc, e);

  // ---- bf16 operand prep ----
  long n8a = (long)n * 512 / 8;
  cvt_a_bf16<<<(int)((n8a + 255) / 256), 256, 0, stream>>>(features, A1b, n8a);
  cvt_w_t<<<(512 * 512 + 255) / 256, 256, 0, stream>>>(W1, W1t, 512, 512);
  cvt_w_t<<<(512 * 320 + 255) / 256, 256, 0, stream>>>(W2, W2t, 512, 320);

  // ---- layer 1 ----
  dim3 g1(Mp / 128, 512 / 128);
  gemm_bf16<<<g1, 256, 0, stream>>>(A1b, W1t, feat1, feat1b, n, 512, 512);
  el_er_kernel<<<(n * 8 + 255) / 256, 256, 0, stream>>>(feat1, al1, ar1, el1, er1, n, 64);
  aggregate1<<<(n + 3) / 4, 256, 0, stream>>>(feat1b, el1, er1, offsets, ssrc, b1, hb, n);

  // ---- layer 2 ---- (feat2 overwrites feat1b — dead; hb overwrote A1b — dead)
  dim3 g2(Mp / 128, 384 / 128);
  gemm_bf16<<<g2, 256, 0, stream>>>(hb, W2t, feat2, (bf16_t*)nullptr, n, 320, 512);
  el_er_kernel<<<(n * 8 + 255) / 256, 256, 0, stream>>>(feat2, al2, ar2, el2, er2, n, 40);
  aggregate2<<<(n + 3) / 4, 256, 0, stream>>>(feat2, el2, er2, offsets, ssrc, b2, out2, n);

  mean_heads<<<(n * 40 + 255) / 256, 256, 0, stream>>>(out2, out, n);
}

// Round 6
// 528.751 us; speedup vs baseline: 4.2206x; 1.3752x over previous
//
#include <hip/hip_runtime.h>
#include <cstdint>
#include <cstddef>

#define SLOPE 0.2f
#define HEADS 8

typedef __bf16 bf16_t;
typedef __bf16 bf16x8 __attribute__((ext_vector_type(8)));
typedef float f32x4 __attribute__((ext_vector_type(4)));

// ---------------- fp32 -> bf16 row-major convert (8 elems/thread) ----------------
__global__ void cvt_a_bf16(const float* __restrict__ in, bf16_t* __restrict__ out, long n8) {
  long gid = (long)blockIdx.x * blockDim.x + threadIdx.x;
  if (gid >= n8) return;
  const float4* ip = (const float4*)in;
  float4 v0 = ip[gid * 2], v1 = ip[gid * 2 + 1];
  bf16x8 o;
  o[0] = (bf16_t)v0.x; o[1] = (bf16_t)v0.y; o[2] = (bf16_t)v0.z; o[3] = (bf16_t)v0.w;
  o[4] = (bf16_t)v1.x; o[5] = (bf16_t)v1.y; o[6] = (bf16_t)v1.z; o[7] = (bf16_t)v1.w;
  ((bf16x8*)out)[gid] = o;
}

// ---------------- W [K,N] fp32 -> Bt [N,K] bf16 (transpose) ----------------
__global__ void cvt_w_t(const float* __restrict__ W, bf16_t* __restrict__ Bt, int K, int N) {
  int gid = blockIdx.x * blockDim.x + threadIdx.x;
  if (gid >= K * N) return;
  int nn = gid / K, kk = gid % K;
  Bt[gid] = (bf16_t)W[(size_t)kk * N + nn];
}

// ---------------- bf16 MFMA GEMM: Cb[M,Nc] = A[Mp,K] * Bt[Np,K]^T, bf16 out ----------------
// 128x128 tile, BK=64, 4 waves (2x2). Column-tile = blockIdx.x (fast dim) so the
// tiles sharing the same A rows are dispatched back-to-back -> A re-reads hit L2/L3.
__global__ __launch_bounds__(256) void gemm_bf16(
    const bf16_t* __restrict__ A,   // [Mp][K] row-major bf16 (Mp multiple of 128, pads zeroed)
    const bf16_t* __restrict__ Bt,  // [Np][K] row-major bf16 (Np multiple of 128, pads zeroed)
    bf16_t* __restrict__ Cb,        // [M][Nc] bf16
    int M, int Nc, int K) {
  __shared__ __align__(16) unsigned char lds[32768];  // A: [0,16K), B: [16K,32K)
  const int tid = threadIdx.x;
  const int wid = tid >> 6, lane = tid & 63;
  const int wm = wid >> 1, wn = wid & 1;
  const int bm = blockIdx.y * 128, bn = blockIdx.x * 128;  // column tiles fastest
  const int quad = lane >> 4, lrow = lane & 15;

  f32x4 acc[4][4] = {};

  const int st_sub = wid * 8 + (lane >> 3);            // row within 32-row group
  const int st_k = 8 * ((lane & 7) ^ (lane >> 3));     // pre-swizzled source k
  const bf16_t* aSrc = A + (size_t)(bm + st_sub) * K + st_k;
  const bf16_t* bSrc = Bt + (size_t)(bn + st_sub) * K + st_k;

  const int xorv = (lrow & 7) << 4;
  const int aRdBase = (wm * 64 + lrow) * 128;          // + mf*2048 + kb
  const int bRdBase = (wn * 64 + lrow) * 128 + 16384;  // + nf*2048 + kb

  for (int k0 = 0; k0 < K; k0 += 64) {
    if (k0) __syncthreads();
#pragma unroll
    for (int i = 0; i < 4; ++i) {
      __builtin_amdgcn_global_load_lds(
          (const __attribute__((address_space(1))) void*)(aSrc + (size_t)i * 32 * K + k0),
          (__attribute__((address_space(3))) void*)(lds + (i * 4 + wid) * 1024), 16, 0, 0);
    }
#pragma unroll
    for (int i = 0; i < 4; ++i) {
      __builtin_amdgcn_global_load_lds(
          (const __attribute__((address_space(1))) void*)(bSrc + (size_t)i * 32 * K + k0),
          (__attribute__((address_space(3))) void*)(lds + 16384 + (i * 4 + wid) * 1024), 16, 0, 0);
    }
    __syncthreads();
#pragma unroll
    for (int kk = 0; kk < 2; ++kk) {
      bf16x8 af[4], bfr[4];
      const int kb = (kk * 64 + quad * 16) ^ xorv;
#pragma unroll
      for (int mf = 0; mf < 4; ++mf)
        af[mf] = *(const bf16x8*)(lds + aRdBase + mf * 2048 + kb);
#pragma unroll
      for (int nf = 0; nf < 4; ++nf)
        bfr[nf] = *(const bf16x8*)(lds + bRdBase + nf * 2048 + kb);
#pragma unroll
      for (int mf = 0; mf < 4; ++mf)
#pragma unroll
        for (int nf = 0; nf < 4; ++nf)
          acc[mf][nf] =
              __builtin_amdgcn_mfma_f32_16x16x32_bf16(af[mf], bfr[nf], acc[mf][nf], 0, 0, 0);
    }
  }

  // C/D layout (verified m89/m91): col = lane&15, row = (lane>>4)*4 + reg
  const int crow0 = bm + wm * 64 + quad * 4;
  const int ccol0 = bn + wn * 64 + lrow;
#pragma unroll
  for (int mf = 0; mf < 4; ++mf) {
#pragma unroll
    for (int r = 0; r < 4; ++r) {
      int row = crow0 + mf * 16 + r;
      if (row < M) {
#pragma unroll
        for (int nf = 0; nf < 4; ++nf) {
          int col = ccol0 + nf * 16;
          if (col < Nc) Cb[(size_t)row * Nc + col] = (bf16_t)acc[mf][nf][r];
        }
      }
    }
  }
}

// ---------------- el/er from bf16 feat: per (node, head) dot with al/ar ----------------
__global__ void el_er_b(const bf16_t* __restrict__ featb, const float* __restrict__ al,
                        const float* __restrict__ ar, float* __restrict__ el,
                        float* __restrict__ er, int n, int D) {
  int gid = blockIdx.x * blockDim.x + threadIdx.x;
  if (gid >= n * HEADS) return;
  int node = gid >> 3, h = gid & 7;
  const bf16_t* f = featb + (size_t)node * HEADS * D + h * D;
  const float* alp = al + h * D;
  const float* arp = ar + h * D;
  float a = 0.f, b = 0.f;
  for (int d = 0; d < D; d += 8) {
    bf16x8 v = *(const bf16x8*)(f + d);
#pragma unroll
    for (int i = 0; i < 8; ++i) {
      float x = (float)v[i];
      a = fmaf(x, alp[d + i], a);
      b = fmaf(x, arp[d + i], b);
    }
  }
  el[gid] = a;
  er[gid] = b;
}

// ---------------- CSR build ----------------
__global__ void count_deg(const int* __restrict__ dst, int* __restrict__ deg, int e) {
  int gid = blockIdx.x * blockDim.x + threadIdx.x;
  if (gid < e) atomicAdd(&deg[dst[gid]], 1);
}

__global__ void scan_block(const int* __restrict__ deg, int* __restrict__ incl,
                           int* __restrict__ bsum, int n) {
  __shared__ int tmp[256];
  int t = threadIdx.x;
  int gid = blockIdx.x * 256 + t;
  int v = (gid < n) ? deg[gid] : 0;
  tmp[t] = v;
  __syncthreads();
  for (int off = 1; off < 256; off <<= 1) {
    int x = (t >= off) ? tmp[t - off] : 0;
    __syncthreads();
    tmp[t] += x;
    __syncthreads();
  }
  if (gid < n) incl[gid] = tmp[t];
  if (t == 255) bsum[blockIdx.x] = tmp[255];
}

__global__ void scan_small(const int* __restrict__ bsum, int* __restrict__ bbase, int nb) {
  __shared__ int tmp[512];
  int t = threadIdx.x;
  int v = (t < nb) ? bsum[t] : 0;
  tmp[t] = v;
  __syncthreads();
  for (int off = 1; off < 512; off <<= 1) {
    int x = (t >= off) ? tmp[t - off] : 0;
    __syncthreads();
    tmp[t] += x;
    __syncthreads();
  }
  if (t < nb) bbase[t] = tmp[t] - v;  // exclusive
}

__global__ void finalize_offsets(const int* __restrict__ incl, const int* __restrict__ deg,
                                 const int* __restrict__ bbase, int* __restrict__ offsets,
                                 int n) {
  int gid = blockIdx.x * blockDim.x + threadIdx.x;
  if (gid >= n) return;
  int base = bbase[gid >> 8];
  offsets[gid] = incl[gid] - deg[gid] + base;
  if (gid == n - 1) offsets[n] = incl[gid] + base;
}

__global__ void scatter_edges(const int* __restrict__ src, const int* __restrict__ dst,
                              const int* __restrict__ offsets, int* __restrict__ cursor,
                              int* __restrict__ ssrc, int e) {
  int gid = blockIdx.x * blockDim.x + threadIdx.x;
  if (gid < e) {
    int d = dst[gid];
    int p = offsets[d] + atomicAdd(&cursor[d], 1);
    ssrc[p] = src[gid];
  }
}

// ---------------- wave-per-node online softmax (shared by both aggregates) ----------------
// lane = h*8 + strip. Returns (m, ss) valid in every lane of the 8-lane head group.
__device__ inline void wave_softmax_stats(const float* __restrict__ el, float er_h, int h,
                                          int strip, const int* __restrict__ ssrc, int s0,
                                          int s1, float& m, float& ss) {
  m = -INFINITY;
  ss = 0.f;
  for (int j = s0 + strip; j < s1; j += 8) {
    int s = ssrc[j];
    float x = el[s * HEADS + h] + er_h;
    x = x > 0.f ? x : SLOPE * x;
    if (x > m) {
      ss = ss * __expf(m - x) + 1.f;
      m = x;
    } else {
      ss += __expf(x - m);
    }
  }
#pragma unroll
  for (int mask = 1; mask < 8; mask <<= 1) {
    float mo = __shfl_xor(m, mask, 64);
    float so = __shfl_xor(ss, mask, 64);
    float mn = fmaxf(m, mo);
    float e1 = (m == -INFINITY) ? 0.f : __expf(m - mn);
    float e2 = (mo == -INFINITY) ? 0.f : __expf(mo - mn);
    ss = ss * e1 + so * e2;
    m = mn;
  }
}

// ---------------- layer-1 aggregate: HD=512, D=64, bf16 gather, relu, bf16 out ----------------
__global__ __launch_bounds__(256) void aggregate1(
    const bf16_t* __restrict__ featb, const float* __restrict__ el,
    const float* __restrict__ er, const int* __restrict__ offsets,
    const int* __restrict__ ssrc, const float* __restrict__ bias,
    bf16_t* __restrict__ outb, int n) {
  int wid = threadIdx.x >> 6, lane = threadIdx.x & 63;
  int node = blockIdx.x * 4 + wid;
  if (node >= n) return;
  int s0 = offsets[node], s1 = offsets[node + 1];
  int h = lane >> 3, strip = lane & 7;
  float er_h = er[node * HEADS + h];
  float m, ss;
  wave_softmax_stats(el, er_h, h, strip, ssrc, s0, s1, m, ss);
  float inv_ss = 1.f / ss;

  float acc[8] = {};
  for (int j = s0; j < s1; ++j) {
    int s = ssrc[j];
    float x = el[s * HEADS + h] + er_h;
    x = x > 0.f ? x : SLOPE * x;
    float alpha = __expf(x - m) * inv_ss;
    bf16x8 fv = *(const bf16x8*)(featb + (size_t)s * 512 + lane * 8);
#pragma unroll
    for (int i = 0; i < 8; ++i) acc[i] += alpha * (float)fv[i];
  }
  bf16x8 o;
#pragma unroll
  for (int i = 0; i < 8; ++i) {
    float v = acc[i] + bias[lane * 8 + i];
    o[i] = (bf16_t)fmaxf(v, 0.f);
  }
  *(bf16x8*)(outb + (size_t)node * 512 + lane * 8) = o;
}

// ---------------- layer-2 aggregate: HD=320, D=40, bf16 gather, fused head-mean ----------------
__global__ __launch_bounds__(256) void aggregate2(
    const bf16_t* __restrict__ featb, const float* __restrict__ el,
    const float* __restrict__ er, const int* __restrict__ offsets,
    const int* __restrict__ ssrc, const float* __restrict__ bias,
    float* __restrict__ out, int n) {
  __shared__ float red[4][320];
  int wid = threadIdx.x >> 6, lane = threadIdx.x & 63;
  int node = blockIdx.x * 4 + wid;
  if (node >= n) return;  // n % 4 == 0 here; no divergence in practice (no barriers below anyway)
  int s0 = offsets[node], s1 = offsets[node + 1];
  int h = lane >> 3, strip = lane & 7;
  float er_h = er[node * HEADS + h];
  float m, ss;
  wave_softmax_stats(el, er_h, h, strip, ssrc, s0, s1, m, ss);
  float inv_ss = 1.f / ss;

  // element d = lane + k*64, alpha source lane = (d/40)*8 (static per k after unroll)
  int alane0 = ((lane + 0 * 64) / 40) * 8;
  int alane1 = ((lane + 1 * 64) / 40) * 8;
  int alane2 = ((lane + 2 * 64) / 40) * 8;
  int alane3 = ((lane + 3 * 64) / 40) * 8;
  int alane4 = ((lane + 4 * 64) / 40) * 8;

  float acc[5] = {};
  for (int j = s0; j < s1; ++j) {
    int s = ssrc[j];
    float x = el[s * HEADS + h] + er_h;
    x = x > 0.f ? x : SLOPE * x;
    float aown = __expf(x - m) * inv_ss;  // alpha for this lane's head h
    const bf16_t* fp = featb + (size_t)s * 320;
    acc[0] += __shfl(aown, alane0, 64) * (float)fp[lane];
    acc[1] += __shfl(aown, alane1, 64) * (float)fp[lane + 64];
    acc[2] += __shfl(aown, alane2, 64) * (float)fp[lane + 128];
    acc[3] += __shfl(aown, alane3, 64) * (float)fp[lane + 192];
    acc[4] += __shfl(aown, alane4, 64) * (float)fp[lane + 256];
  }
  // per-wave LDS reduce over heads: out[node][c] = (1/8) * sum_h (acc[h*40+c] + bias)
#pragma unroll
  for (int k = 0; k < 5; ++k) {
    int d = lane + k * 64;
    red[wid][d] = acc[k] + bias[d];
  }
  // wave-internal ordering: DS ops complete in order per wave; drain + fence scheduler
  __builtin_amdgcn_wave_barrier();
  asm volatile("s_waitcnt lgkmcnt(0)" ::: "memory");
  __builtin_amdgcn_wave_barrier();
  if (lane < 40) {
    float s = 0.f;
#pragma unroll
    for (int hh = 0; hh < HEADS; ++hh) s += red[wid][hh * 40 + lane];
    out[(size_t)node * 40 + lane] = s * 0.125f;
  }
}

extern "C" void kernel_launch(void* const* d_in, const int* in_sizes, int n_in,
                              void* d_out, int out_size, void* d_ws, size_t ws_size,
                              hipStream_t stream) {
  const float* features = (const float*)d_in[0];
  const float* W1 = (const float*)d_in[1];
  const float* al1 = (const float*)d_in[2];
  const float* ar1 = (const float*)d_in[3];
  const float* b1 = (const float*)d_in[4];
  const float* W2 = (const float*)d_in[5];
  const float* al2 = (const float*)d_in[6];
  const float* ar2 = (const float*)d_in[7];
  const float* b2 = (const float*)d_in[8];
  const int* src = (const int*)d_in[9];
  const int* dst = (const int*)d_in[10];
  float* out = (float*)d_out;

  const int n = in_sizes[0] / 512;         // 100000
  const int e = in_sizes[9];               // 500000
  const int Mp = ((n + 127) / 128) * 128;  // 100096

  char* p = (char*)d_ws;
  auto alloc = [&](size_t bytes) {
    char* r = p;
    p += (bytes + 255) & ~(size_t)255;
    return r;
  };
  // RA: feat1b bf16 [n,512] (gemm L1 out; dead after aggregate1)
  //     -> feat2b bf16 [n,320] (born at gemm L2).
  bf16_t* feat1b = (bf16_t*)alloc((size_t)n * 512 * 2);  // 102.4 MB
  bf16_t* feat2b = feat1b;
  // RB: A1b bf16 [Mp,512] (cvt out, gemm L1 in; dead after gemm L1)
  //     -> hb bf16 [Mp,512] (aggregate1 out rows [0,n); pad rows stay zeroed from A1b init).
  bf16_t* A1b = (bf16_t*)alloc((size_t)Mp * 512 * 2);  // 102.5 MB
  bf16_t* hb = A1b;
  bf16_t* W1t = (bf16_t*)alloc((size_t)512 * 512 * 2);
  bf16_t* W2t = (bf16_t*)alloc((size_t)384 * 512 * 2);
  float* el1 = (float*)alloc((size_t)n * 8 * 4);
  float* er1 = (float*)alloc((size_t)n * 8 * 4);
  float* el2 = (float*)alloc((size_t)n * 8 * 4);
  float* er2 = (float*)alloc((size_t)n * 8 * 4);
  int* deg = (int*)alloc((size_t)n * 4);
  int* cursor = (int*)alloc((size_t)n * 4);
  int* incl = (int*)alloc((size_t)n * 4);
  int* offsets = (int*)alloc((size_t)(n + 1) * 4);
  int nb = (n + 255) / 256;
  int* bsum = (int*)alloc((size_t)nb * 4);
  int* bbase = (int*)alloc((size_t)nb * 4);
  int* ssrc = (int*)alloc((size_t)e * 4);
  // total ~225 MB

  hipMemsetAsync(deg, 0, (size_t)n * 4, stream);
  hipMemsetAsync(cursor, 0, (size_t)n * 4, stream);
  // Zero pad regions read by gemm kernels (A1b/hb pads persist zeroed; W2t pad rows).
  hipMemsetAsync(A1b + (size_t)n * 512, 0, (size_t)(Mp - n) * 512 * 2, stream);
  hipMemsetAsync(W2t + (size_t)320 * 512, 0, (size_t)64 * 512 * 2, stream);

  int eb = (e + 255) / 256;
  count_deg<<<eb, 256, 0, stream>>>(dst, deg, e);
  scan_block<<<nb, 256, 0, stream>>>(deg, incl, bsum, n);
  scan_small<<<1, 512, 0, stream>>>(bsum, bbase, nb);
  finalize_offsets<<<nb, 256, 0, stream>>>(incl, deg, bbase, offsets, n);
  scatter_edges<<<eb, 256, 0, stream>>>(src, dst, offsets, cursor, ssrc, e);

  // ---- bf16 operand prep ----
  long n8a = (long)n * 512 / 8;
  cvt_a_bf16<<<(int)((n8a + 255) / 256), 256, 0, stream>>>(features, A1b, n8a);
  cvt_w_t<<<(512 * 512 + 255) / 256, 256, 0, stream>>>(W1, W1t, 512, 512);
  cvt_w_t<<<(512 * 320 + 255) / 256, 256, 0, stream>>>(W2, W2t, 512, 320);

  // ---- layer 1 ----
  dim3 g1(512 / 128, Mp / 128);  // column tiles fastest
  gemm_bf16<<<g1, 256, 0, stream>>>(A1b, W1t, feat1b, n, 512, 512);
  el_er_b<<<(n * 8 + 255) / 256, 256, 0, stream>>>(feat1b, al1, ar1, el1, er1, n, 64);
  aggregate1<<<(n + 3) / 4, 256, 0, stream>>>(feat1b, el1, er1, offsets, ssrc, b1, hb, n);

  // ---- layer 2 ---- (feat2b overwrites feat1b — dead; hb overwrote A1b — dead)
  dim3 g2(384 / 128, Mp / 128);
  gemm_bf16<<<g2, 256, 0, stream>>>(hb, W2t, feat2b, n, 320, 512);
  el_er_b<<<(n * 8 + 255) / 256, 256, 0, stream>>>(feat2b, al2, ar2, el2, er2, n, 40);
  aggregate2<<<(n + 3) / 4, 256, 0, stream>>>(feat2b, el2, er2, offsets, ssrc, b2, out, n);
}